// Round 1
// baseline (317.767 us; speedup 1.0000x reference)
//
#include <hip/hip_runtime.h>
#include <hip/hip_bf16.h>

#define SEQ  2048
#define DIM  2048
#define NQK  3072   // q(2048) + k(512) + v(512) columns
#define NH   32
#define NKV  8
#define HD   64

typedef __attribute__((ext_vector_type(8))) short s8v;
typedef __attribute__((ext_vector_type(4))) short s4v;
typedef __attribute__((ext_vector_type(4))) float f32x4;

__device__ __forceinline__ short f2bf_bits(float f) {
    __hip_bfloat16 b = __float2bfloat16(f);
    short s; __builtin_memcpy(&s, &b, 2); return s;
}
__device__ __forceinline__ float bfbits2f(short s) {
    __hip_bfloat16 b; __builtin_memcpy(&b, &s, 2);
    return __bfloat162float(b);
}
__device__ __forceinline__ f32x4 mfma16(s8v a, s8v b, f32x4 c) {
    return __builtin_amdgcn_mfma_f32_16x16x32_bf16(a, b, c, 0, 0, 0);
}
__device__ __forceinline__ void load16_to_lds(const void* g, void* l) {
    __builtin_amdgcn_global_load_lds(
        (const __attribute__((address_space(1))) void*)g,
        (__attribute__((address_space(3))) void*)l, 16, 0, 0);
}

// ---------------- convert x (fp32 -> bf16) ----------------
__global__ void cvt_f32_bf16(const float* __restrict__ src, short* __restrict__ dst) {
    int i = (blockIdx.x * 256 + threadIdx.x) * 4;
    float4 v = *(const float4*)(src + i);
    s4v o;
    o.x = f2bf_bits(v.x); o.y = f2bf_bits(v.y);
    o.z = f2bf_bits(v.z); o.w = f2bf_bits(v.w);
    *(s4v*)(dst + i) = o;
}

// ---------------- transpose + convert (K x Cs fp32 -> Cs x 2048 bf16) ----------------
__global__ void transpose_cvt(const float* __restrict__ src, short* __restrict__ dst, int Cs) {
    __shared__ float tile[32][33];
    int bx = blockIdx.x * 32, by = blockIdx.y * 32;
    int tx = threadIdx.x, ty = threadIdx.y;   // 32 x 8
    #pragma unroll
    for (int j = 0; j < 32; j += 8)
        tile[ty + j][tx] = src[(size_t)(by + ty + j) * Cs + bx + tx];
    __syncthreads();
    #pragma unroll
    for (int j = 0; j < 32; j += 8)
        dst[(size_t)(bx + ty + j) * 2048 + by + tx] = f2bf_bits(tile[tx][ty + j]);
}

// ---------------- GEMM: A (MxK bf16) @ BT (NxK bf16)^T -> C (MxN) ----------------
template<bool F32OUT>
__global__ __launch_bounds__(256, 2)
void gemm_bt(const short* __restrict__ A, const short* __restrict__ BT,
             void* __restrict__ C, int M, int N, int K)
{
    __shared__ short As[128 * 64];
    __shared__ short Bs[128 * 64];
    const int lane = threadIdx.x & 63;
    const int wid  = threadIdx.x >> 6;
    const int r = lane & 15, g = lane >> 4;
    const int bm = blockIdx.y * 128, bn = blockIdx.x * 128;
    const int wm = (wid >> 1) * 64, wn = (wid & 1) * 64;

    f32x4 acc[4][4];
    #pragma unroll
    for (int i = 0; i < 4; ++i)
        #pragma unroll
        for (int j = 0; j < 4; ++j) acc[i][j] = (f32x4){0.f, 0.f, 0.f, 0.f};

    const int srow = wid * 32 + (lane >> 3);   // wave w stages rows [w*32, w*32+32)
    const int scol = (lane & 7) * 8;

    for (int k0 = 0; k0 < K; k0 += 64) {
        #pragma unroll
        for (int s2 = 0; s2 < 4; ++s2) {
            int row = srow + s2 * 8;
            int seg = wid * 4 + s2;
            load16_to_lds(A  + (size_t)(bm + row) * K + k0 + scol, As + seg * 512);
            load16_to_lds(BT + (size_t)(bn + row) * K + k0 + scol, Bs + seg * 512);
        }
        __syncthreads();
        #pragma unroll
        for (int kk = 0; kk < 64; kk += 32) {
            s8v a[4], b[4];
            #pragma unroll
            for (int t = 0; t < 4; ++t)
                a[t] = *(const s8v*)&As[(wm + t * 16 + r) * 64 + kk + g * 8];
            #pragma unroll
            for (int t = 0; t < 4; ++t)
                b[t] = *(const s8v*)&Bs[(wn + t * 16 + r) * 64 + kk + g * 8];
            #pragma unroll
            for (int i = 0; i < 4; ++i)
                #pragma unroll
                for (int j = 0; j < 4; ++j)
                    acc[i][j] = mfma16(a[i], b[j], acc[i][j]);
        }
        __syncthreads();
    }
    #pragma unroll
    for (int i = 0; i < 4; ++i)
        #pragma unroll
        for (int j = 0; j < 4; ++j)
            #pragma unroll
            for (int q = 0; q < 4; ++q) {
                int row = bm + wm + i * 16 + g * 4 + q;
                int col = bn + wn + j * 16 + r;
                float v = acc[i][j][q];
                if (F32OUT) ((float*)C)[(size_t)row * N + col] = v;
                else        ((short*)C)[(size_t)row * N + col] = f2bf_bits(v);
            }
}

// ---------------- RoPE (in-place on bf16 qkv; Q + K heads) ----------------
__global__ void rope_kernel(short* __restrict__ qkv,
                            const float* __restrict__ fc, const float* __restrict__ fs) {
    int idx = blockIdx.x * 256 + threadIdx.x;   // SEQ * 1280 total
    int s = idx / 1280;
    int p = idx - s * 1280;
    int col, i;
    if (p < 1024) { i = p & 31; col = (p >> 5) * 64 + 2 * i; }
    else { int pk = p - 1024; i = pk & 31; col = 2048 + (pk >> 5) * 64 + 2 * i; }
    short* base = qkv + (size_t)s * NQK + col;
    float xe = bfbits2f(base[0]);
    float xo = bfbits2f(base[1]);
    float c = fc[s * 32 + i], sn = fs[s * 32 + i];
    base[0] = f2bf_bits(xe * c - xo * sn);
    base[1] = f2bf_bits(xe * sn + xo * c);
}

// ---------------- flash attention: 1 head x 64 q-rows per block ----------------
__global__ __launch_bounds__(256, 2)
void flash_attn(const short* __restrict__ qkv, short* __restrict__ O) {
    const int h  = blockIdx.x;          // 0..31
    const int qb = blockIdx.y * 64;     // q block base
    const int kh = h >> 2;              // GQA: kv head
    const int lane = threadIdx.x & 63;
    const int wid  = threadIdx.x >> 6;
    const int r = lane & 15, g = lane >> 4;

    __shared__ short Ks[64][72];        // [kpos][d]   (pad 72 -> 144B rows)
    __shared__ short Vt[64][72];        // [d][kpos]
    __shared__ short Pl[4][16][72];     // per-wave P  [qrow][kpos]

    // Q fragments for this wave's 16 rows (A-operand: row = lane&15)
    s8v qf0, qf1;
    {
        const short* qrow = qkv + (size_t)(qb + wid * 16 + r) * NQK + h * 64;
        qf0 = *(const s8v*)(qrow + g * 8);
        qf1 = *(const s8v*)(qrow + 32 + g * 8);
    }

    float m[4], l[4];
    f32x4 o[4];
    #pragma unroll
    for (int q = 0; q < 4; ++q) { m[q] = -1e30f; l[q] = 0.f; }
    #pragma unroll
    for (int t = 0; t < 4; ++t) o[t] = (f32x4){0.f, 0.f, 0.f, 0.f};

    const int nkt = blockIdx.y + 1;
    for (int kt = 0; kt < nkt; ++kt) {
        { // stage K tile and V^T tile
            int tr = threadIdx.x >> 2;
            int tc = (threadIdx.x & 3) * 16;
            const short* kg = qkv + (size_t)(kt * 64 + tr) * NQK + 2048 + kh * 64 + tc;
            *(s8v*)&Ks[tr][tc]     = *(const s8v*)kg;
            *(s8v*)&Ks[tr][tc + 8] = *(const s8v*)(kg + 8);
            const short* vg = qkv + (size_t)(kt * 64 + tr) * NQK + 2560 + kh * 64 + tc;
            s8v v0 = *(const s8v*)vg;
            s8v v1 = *(const s8v*)(vg + 8);
            #pragma unroll
            for (int j = 0; j < 8; ++j) Vt[tc + j][tr]     = v0[j];
            #pragma unroll
            for (int j = 0; j < 8; ++j) Vt[tc + 8 + j][tr] = v1[j];
        }
        __syncthreads();

        // S = Q @ K^T  (16 x 64 per wave)
        f32x4 s[4];
        #pragma unroll
        for (int t = 0; t < 4; ++t) {
            s8v kb0 = *(const s8v*)&Ks[t * 16 + r][g * 8];
            s8v kb1 = *(const s8v*)&Ks[t * 16 + r][32 + g * 8];
            f32x4 z = (f32x4){0.f, 0.f, 0.f, 0.f};
            z = mfma16(qf0, kb0, z);
            z = mfma16(qf1, kb1, z);
            s[t] = z;
        }

        // scale + causal mask (only diagonal tile straddles)
        const bool diag = (kt == nkt - 1);
        #pragma unroll
        for (int t = 0; t < 4; ++t)
            #pragma unroll
            for (int q = 0; q < 4; ++q) {
                float v = s[t][q] * 0.125f;
                if (diag) {
                    int qrow = qb + wid * 16 + g * 4 + q;
                    int kpos = kt * 64 + t * 16 + r;
                    if (kpos > qrow) v = -1e30f;
                }
                s[t][q] = v;
            }

        // online softmax: row max (reduce over 4 tiles in-lane + 16 lanes)
        float alpha[4];
        #pragma unroll
        for (int q = 0; q < 4; ++q) {
            float v = fmaxf(fmaxf(s[0][q], s[1][q]), fmaxf(s[2][q], s[3][q]));
            #pragma unroll
            for (int off = 1; off < 16; off <<= 1) v = fmaxf(v, __shfl_xor(v, off, 64));
            float mn = fmaxf(m[q], v);
            alpha[q] = __expf(m[q] - mn);
            m[q] = mn;
        }
        #pragma unroll
        for (int t = 0; t < 4; ++t)
            #pragma unroll
            for (int q = 0; q < 4; ++q)
                s[t][q] = __expf(s[t][q] - m[q]);
        #pragma unroll
        for (int q = 0; q < 4; ++q) {
            float v = s[0][q] + s[1][q] + s[2][q] + s[3][q];
            #pragma unroll
            for (int off = 1; off < 16; off <<= 1) v += __shfl_xor(v, off, 64);
            l[q] = l[q] * alpha[q] + v;
        }

        // rescale O, stash P (bf16) to LDS in C-layout
        #pragma unroll
        for (int t = 0; t < 4; ++t)
            #pragma unroll
            for (int q = 0; q < 4; ++q) {
                o[t][q] *= alpha[q];
                Pl[wid][g * 4 + q][t * 16 + r] = f2bf_bits(s[t][q]);
            }
        asm volatile("s_waitcnt lgkmcnt(0)" ::: "memory");

        // O += P @ V
        s8v pa0 = *(const s8v*)&Pl[wid][r][g * 8];
        s8v pa1 = *(const s8v*)&Pl[wid][r][32 + g * 8];
        #pragma unroll
        for (int t = 0; t < 4; ++t) {
            s8v vb0 = *(const s8v*)&Vt[t * 16 + r][g * 8];
            s8v vb1 = *(const s8v*)&Vt[t * 16 + r][32 + g * 8];
            o[t] = mfma16(pa0, vb0, o[t]);
            o[t] = mfma16(pa1, vb1, o[t]);
        }
        __syncthreads();
    }

    // epilogue: O / l -> bf16 at [s][h*64+d]
    #pragma unroll
    for (int t = 0; t < 4; ++t)
        #pragma unroll
        for (int q = 0; q < 4; ++q) {
            float val = o[t][q] / l[q];
            O[(size_t)(qb + wid * 16 + g * 4 + q) * 2048 + h * 64 + t * 16 + r] = f2bf_bits(val);
        }
}

extern "C" void kernel_launch(void* const* d_in, const int* in_sizes, int n_in,
                              void* d_out, int out_size, void* d_ws, size_t ws_size,
                              hipStream_t stream)
{
    const float* x  = (const float*)d_in[0];
    const float* fc = (const float*)d_in[1];
    const float* fs = (const float*)d_in[2];
    // d_in[3] = mask (unused; causal applied analytically)
    const float* wq = (const float*)d_in[4];
    const float* wk = (const float*)d_in[5];
    const float* wv = (const float*)d_in[6];
    const float* wo = (const float*)d_in[7];
    float* out = (float*)d_out;

    char* ws = (char*)d_ws;
    short* xb    = (short*)(ws);                         //  8 MB: 2048x2048
    short* wqkvT = (short*)(ws + 8  * 1024 * 1024);      // 12 MB: 3072x2048
    short* woT   = (short*)(ws + 20 * 1024 * 1024);      //  8 MB: 2048x2048
    short* qkv   = (short*)(ws + 28 * 1024 * 1024);      // 12 MB: 2048x3072
    short* attnO = (short*)(ws + 40 * 1024 * 1024);      //  8 MB: 2048x2048

    dim3 tb(32, 8);
    cvt_f32_bf16<<<4096, 256, 0, stream>>>(x, xb);
    transpose_cvt<<<dim3(64, 64), tb, 0, stream>>>(wq, wqkvT, 2048);
    transpose_cvt<<<dim3(16, 64), tb, 0, stream>>>(wk, wqkvT + 2048 * 2048, 512);
    transpose_cvt<<<dim3(16, 64), tb, 0, stream>>>(wv, wqkvT + 2560 * 2048, 512);
    transpose_cvt<<<dim3(64, 64), tb, 0, stream>>>(wo, woT, 2048);

    gemm_bt<false><<<dim3(24, 16), 256, 0, stream>>>(xb, wqkvT, qkv, 2048, 3072, 2048);
    rope_kernel<<<10240, 256, 0, stream>>>(qkv, fc, fs);
    flash_attn<<<dim3(32, 32), 256, 0, stream>>>(qkv, attnO);
    gemm_bt<true><<<dim3(16, 16), 256, 0, stream>>>(attnO, woT, out, 2048, 2048, 2048);
}

// Round 2
// 287.771 us; speedup vs baseline: 1.1042x; 1.1042x over previous
//
#include <hip/hip_runtime.h>
#include <hip/hip_bf16.h>

#define SEQ  2048
#define DIM  2048
#define NQK  3072   // q(2048) + k(512) + v(512) columns
#define NH   32
#define NKV  8
#define HD   64

typedef __attribute__((ext_vector_type(8))) short s8v;
typedef __attribute__((ext_vector_type(4))) short s4v;
typedef __attribute__((ext_vector_type(4))) float f32x4;

__device__ __forceinline__ short f2bf_bits(float f) {
    __hip_bfloat16 b = __float2bfloat16(f);
    short s; __builtin_memcpy(&s, &b, 2); return s;
}
__device__ __forceinline__ float bfbits2f(short s) {
    __hip_bfloat16 b; __builtin_memcpy(&b, &s, 2);
    return __bfloat162float(b);
}
__device__ __forceinline__ f32x4 mfma16(s8v a, s8v b, f32x4 c) {
    return __builtin_amdgcn_mfma_f32_16x16x32_bf16(a, b, c, 0, 0, 0);
}
__device__ __forceinline__ void load16_to_lds(const void* g, void* l) {
    __builtin_amdgcn_global_load_lds(
        (const __attribute__((address_space(1))) void*)g,
        (__attribute__((address_space(3))) void*)l, 16, 0, 0);
}

// ---------------- convert x (fp32 -> bf16) ----------------
__global__ void cvt_f32_bf16(const float* __restrict__ src, short* __restrict__ dst) {
    int i = (blockIdx.x * 256 + threadIdx.x) * 4;
    float4 v = *(const float4*)(src + i);
    s4v o;
    o.x = f2bf_bits(v.x); o.y = f2bf_bits(v.y);
    o.z = f2bf_bits(v.z); o.w = f2bf_bits(v.w);
    *(s4v*)(dst + i) = o;
}

// ---------------- transpose + convert (K x Cs fp32 -> Cs x 2048 bf16) ----------------
__global__ void transpose_cvt(const float* __restrict__ src, short* __restrict__ dst, int Cs) {
    __shared__ float tile[32][33];
    int bx = blockIdx.x * 32, by = blockIdx.y * 32;
    int tx = threadIdx.x, ty = threadIdx.y;   // 32 x 8
    #pragma unroll
    for (int j = 0; j < 32; j += 8)
        tile[ty + j][tx] = src[(size_t)(by + ty + j) * Cs + bx + tx];
    __syncthreads();
    #pragma unroll
    for (int j = 0; j < 32; j += 8)
        dst[(size_t)(bx + ty + j) * 2048 + by + tx] = f2bf_bits(tile[tx][ty + j]);
}

// ---------------- GEMM: A (MxK bf16) @ BT (NxK bf16)^T ----------------
// MODE 0: QKV — bf16 out with fused RoPE (cols<2560) and transposed V write (cols>=2560)
// MODE 1: fp32 out plain (out-projection)
template<int MODE>
__global__ __launch_bounds__(256, 2)
void gemm_bt(const short* __restrict__ A, const short* __restrict__ BT,
             void* __restrict__ C, int M, int N, int K,
             short* __restrict__ vT,
             const float* __restrict__ fc, const float* __restrict__ fs)
{
    __shared__ short As[128 * 64];
    __shared__ short Bs[128 * 64];
    const int lane = threadIdx.x & 63;
    const int wid  = threadIdx.x >> 6;
    const int r = lane & 15, g = lane >> 4;
    const int bm = blockIdx.y * 128, bn = blockIdx.x * 128;
    const int wm = (wid >> 1) * 64, wn = (wid & 1) * 64;

    f32x4 acc[4][4];
    #pragma unroll
    for (int i = 0; i < 4; ++i)
        #pragma unroll
        for (int j = 0; j < 4; ++j) acc[i][j] = (f32x4){0.f, 0.f, 0.f, 0.f};

    const int srow = wid * 32 + (lane >> 3);   // wave w stages rows [w*32, w*32+32)
    const int scol = (lane & 7) * 8;

    for (int k0 = 0; k0 < K; k0 += 64) {
        #pragma unroll
        for (int s2 = 0; s2 < 4; ++s2) {
            int row = srow + s2 * 8;
            int seg = wid * 4 + s2;
            load16_to_lds(A  + (size_t)(bm + row) * K + k0 + scol, As + seg * 512);
            load16_to_lds(BT + (size_t)(bn + row) * K + k0 + scol, Bs + seg * 512);
        }
        __syncthreads();
        #pragma unroll
        for (int kk = 0; kk < 64; kk += 32) {
            s8v a[4], b[4];
            #pragma unroll
            for (int t = 0; t < 4; ++t)
                a[t] = *(const s8v*)&As[(wm + t * 16 + r) * 64 + kk + g * 8];
            #pragma unroll
            for (int t = 0; t < 4; ++t)
                b[t] = *(const s8v*)&Bs[(wn + t * 16 + r) * 64 + kk + g * 8];
            __builtin_amdgcn_s_setprio(1);
            #pragma unroll
            for (int i = 0; i < 4; ++i)
                #pragma unroll
                for (int j = 0; j < 4; ++j)
                    acc[i][j] = mfma16(a[i], b[j], acc[i][j]);
            __builtin_amdgcn_s_setprio(0);
        }
        __syncthreads();
    }

    if (MODE == 1) {
        #pragma unroll
        for (int i = 0; i < 4; ++i)
            #pragma unroll
            for (int j = 0; j < 4; ++j)
                #pragma unroll
                for (int q = 0; q < 4; ++q) {
                    int row = bm + wm + i * 16 + g * 4 + q;
                    int col = bn + wn + j * 16 + r;
                    ((float*)C)[(size_t)row * N + col] = acc[i][j][q];
                }
    } else {
        short* qkvO = (short*)C;
        if (bn >= 2560) {
            // V region: write transposed vT[col-2560][row], 4 rows contiguous
            #pragma unroll
            for (int i = 0; i < 4; ++i)
                #pragma unroll
                for (int j = 0; j < 4; ++j) {
                    int row = bm + wm + i * 16 + g * 4;
                    int col = bn + wn + j * 16 + r - 2560;
                    s4v o;
                    #pragma unroll
                    for (int q = 0; q < 4; ++q) o[q] = f2bf_bits(acc[i][j][q]);
                    *(s4v*)&vT[(size_t)col * 2048 + row] = o;
                }
        } else {
            // Q/K region: fused RoPE. col pairs live in adjacent lanes (r, r^1).
            #pragma unroll
            for (int i = 0; i < 4; ++i)
                #pragma unroll
                for (int j = 0; j < 4; ++j) {
                    int row = bm + wm + i * 16 + g * 4;
                    int col = bn + wn + j * 16 + r;
                    int ii  = (col & 63) >> 1;
                    bool odd = (col & 1);
                    #pragma unroll
                    for (int q = 0; q < 4; ++q) {
                        float v = acc[i][j][q];
                        float p = __shfl_xor(v, 1, 64);
                        float c  = fc[(size_t)(row + q) * 32 + ii];
                        float sn = fs[(size_t)(row + q) * 32 + ii];
                        float outv = odd ? (p * sn + v * c) : (v * c - p * sn);
                        qkvO[(size_t)(row + q) * NQK + col] = f2bf_bits(outv);
                    }
                }
        }
    }
}

// ---------------- flash attention: 1 head x 64 q-rows per block ----------------
__global__ __launch_bounds__(256, 4)
void flash_attn(const short* __restrict__ qkv, const short* __restrict__ vT,
                short* __restrict__ O) {
    const int h  = blockIdx.x;                    // 0..31
    const int qi = (int)gridDim.y - 1 - (int)blockIdx.y;  // longest blocks first
    const int qb = qi * 64;
    const int kh = h >> 2;                        // GQA kv head
    const int lane = threadIdx.x & 63;
    const int wid  = threadIdx.x >> 6;
    const int r = lane & 15, g = lane >> 4;

    __shared__ short Ks[64][72];        // [kpos][d]
    __shared__ short Vt[64][72];        // [d][kpos]  (staged from vT, no transpose)
    __shared__ short Pl[4][16][72];     // per-wave P  [qrow][kpos]

    // Q fragments for this wave's 16 rows (A-operand: row = lane&15)
    s8v qf0, qf1;
    {
        const short* qrow = qkv + (size_t)(qb + wid * 16 + r) * NQK + h * 64;
        qf0 = *(const s8v*)(qrow + g * 8);
        qf1 = *(const s8v*)(qrow + 32 + g * 8);
    }

    float m[4], l[4];
    f32x4 o[4];
    #pragma unroll
    for (int q = 0; q < 4; ++q) { m[q] = -1e30f; l[q] = 0.f; }
    #pragma unroll
    for (int t = 0; t < 4; ++t) o[t] = (f32x4){0.f, 0.f, 0.f, 0.f};

    const int tr = threadIdx.x >> 2;          // 0..63
    const int tc = (threadIdx.x & 3) * 16;    // 0,16,32,48

    const int nkt = qi + 1;
    for (int kt = 0; kt < nkt; ++kt) {
        { // stage K tile [kpos][d] and V^T tile [d][kpos] — both vectorized
            const short* kg = qkv + (size_t)(kt * 64 + tr) * NQK + 2048 + kh * 64 + tc;
            *(s8v*)&Ks[tr][tc]     = *(const s8v*)kg;
            *(s8v*)&Ks[tr][tc + 8] = *(const s8v*)(kg + 8);
            const short* vg = vT + (size_t)(kh * 64 + tr) * 2048 + kt * 64 + tc;
            *(s8v*)&Vt[tr][tc]     = *(const s8v*)vg;
            *(s8v*)&Vt[tr][tc + 8] = *(const s8v*)(vg + 8);
        }
        __syncthreads();

        // S = Q @ K^T  (16 x 64 per wave)
        f32x4 s[4];
        __builtin_amdgcn_s_setprio(1);
        #pragma unroll
        for (int t = 0; t < 4; ++t) {
            s8v kb0 = *(const s8v*)&Ks[t * 16 + r][g * 8];
            s8v kb1 = *(const s8v*)&Ks[t * 16 + r][32 + g * 8];
            f32x4 z = (f32x4){0.f, 0.f, 0.f, 0.f};
            z = mfma16(qf0, kb0, z);
            z = mfma16(qf1, kb1, z);
            s[t] = z;
        }
        __builtin_amdgcn_s_setprio(0);

        // scale + causal mask (only the diagonal tile straddles)
        const bool diag = (kt == nkt - 1);
        #pragma unroll
        for (int t = 0; t < 4; ++t)
            #pragma unroll
            for (int q = 0; q < 4; ++q) {
                float v = s[t][q] * 0.125f;
                if (diag) {
                    int qrow = qb + wid * 16 + g * 4 + q;
                    int kpos = kt * 64 + t * 16 + r;
                    if (kpos > qrow) v = -1e30f;
                }
                s[t][q] = v;
            }

        // online softmax
        float alpha[4];
        #pragma unroll
        for (int q = 0; q < 4; ++q) {
            float v = fmaxf(fmaxf(s[0][q], s[1][q]), fmaxf(s[2][q], s[3][q]));
            #pragma unroll
            for (int off = 1; off < 16; off <<= 1) v = fmaxf(v, __shfl_xor(v, off, 64));
            float mn = fmaxf(m[q], v);
            alpha[q] = __expf(m[q] - mn);
            m[q] = mn;
        }
        #pragma unroll
        for (int t = 0; t < 4; ++t)
            #pragma unroll
            for (int q = 0; q < 4; ++q)
                s[t][q] = __expf(s[t][q] - m[q]);
        #pragma unroll
        for (int q = 0; q < 4; ++q) {
            float v = s[0][q] + s[1][q] + s[2][q] + s[3][q];
            #pragma unroll
            for (int off = 1; off < 16; off <<= 1) v += __shfl_xor(v, off, 64);
            l[q] = l[q] * alpha[q] + v;
        }

        // rescale O, stash P (bf16) to LDS in C-layout
        #pragma unroll
        for (int t = 0; t < 4; ++t)
            #pragma unroll
            for (int q = 0; q < 4; ++q) {
                o[t][q] *= alpha[q];
                Pl[wid][g * 4 + q][t * 16 + r] = f2bf_bits(s[t][q]);
            }
        asm volatile("s_waitcnt lgkmcnt(0)" ::: "memory");

        // O += P @ V
        s8v pa0 = *(const s8v*)&Pl[wid][r][g * 8];
        s8v pa1 = *(const s8v*)&Pl[wid][r][32 + g * 8];
        __builtin_amdgcn_s_setprio(1);
        #pragma unroll
        for (int t = 0; t < 4; ++t) {
            s8v vb0 = *(const s8v*)&Vt[t * 16 + r][g * 8];
            s8v vb1 = *(const s8v*)&Vt[t * 16 + r][32 + g * 8];
            o[t] = mfma16(pa0, vb0, o[t]);
            o[t] = mfma16(pa1, vb1, o[t]);
        }
        __builtin_amdgcn_s_setprio(0);
        __syncthreads();
    }

    // epilogue: O / l -> bf16 at [s][h*64+d]
    #pragma unroll
    for (int t = 0; t < 4; ++t)
        #pragma unroll
        for (int q = 0; q < 4; ++q) {
            float val = o[t][q] / l[q];
            O[(size_t)(qb + wid * 16 + g * 4 + q) * 2048 + h * 64 + t * 16 + r] = f2bf_bits(val);
        }
}

extern "C" void kernel_launch(void* const* d_in, const int* in_sizes, int n_in,
                              void* d_out, int out_size, void* d_ws, size_t ws_size,
                              hipStream_t stream)
{
    const float* x  = (const float*)d_in[0];
    const float* fc = (const float*)d_in[1];
    const float* fs = (const float*)d_in[2];
    // d_in[3] = mask (unused; causal applied analytically)
    const float* wq = (const float*)d_in[4];
    const float* wk = (const float*)d_in[5];
    const float* wv = (const float*)d_in[6];
    const float* wo = (const float*)d_in[7];
    float* out = (float*)d_out;

    char* ws = (char*)d_ws;
    short* xb    = (short*)(ws);                         //  8 MB: 2048x2048
    short* wqkvT = (short*)(ws + 8  * 1024 * 1024);      // 12 MB: 3072x2048
    short* woT   = (short*)(ws + 20 * 1024 * 1024);      //  8 MB: 2048x2048
    short* qkv   = (short*)(ws + 28 * 1024 * 1024);      // 12 MB: 2048x3072 (v region unused)
    short* vT    = (short*)(ws + 40 * 1024 * 1024);      //  2 MB: 512x2048 (V transposed)
    short* attnO = (short*)(ws + 42 * 1024 * 1024);      //  8 MB: 2048x2048

    dim3 tb(32, 8);
    cvt_f32_bf16<<<4096, 256, 0, stream>>>(x, xb);
    transpose_cvt<<<dim3(64, 64), tb, 0, stream>>>(wq, wqkvT, 2048);
    transpose_cvt<<<dim3(16, 64), tb, 0, stream>>>(wk, wqkvT + 2048 * 2048, 512);
    transpose_cvt<<<dim3(16, 64), tb, 0, stream>>>(wv, wqkvT + 2560 * 2048, 512);
    transpose_cvt<<<dim3(64, 64), tb, 0, stream>>>(wo, woT, 2048);

    gemm_bt<0><<<dim3(24, 16), 256, 0, stream>>>(xb, wqkvT, qkv, 2048, 3072, 2048, vT, fc, fs);
    flash_attn<<<dim3(32, 32), 256, 0, stream>>>(qkv, vT, attnO);
    gemm_bt<1><<<dim3(16, 16), 256, 0, stream>>>(attnO, woT, out, 2048, 2048, 2048, nullptr, nullptr, nullptr);
}